// Round 1
// baseline (1359.464 us; speedup 1.0000x reference)
//
#include <hip/hip_runtime.h>

// GCN forward: N=100k nodes, E=3.2M edges, G=1024 graphs.
// Layers: GCNConv(6->64) + leakyrelu, GCNConv(64->32) + leakyrelu,
// mean-pool per graph, linear 32->2.
//
// Formulation: with dis[n] = rsqrt(deg[n]) (deg includes self-loop),
//   agg[n] = dis[n] * ( t[n] + sum_{e: dst[e]=n} t[src[e]] ),  t = (x@W)*dis
// then out = leakyrelu(agg + b).

#define N_NODES 100000
#define N_EDGES 3200000
#define N_GRAPHS 1024
#define IN_F 6
#define H1 64
#define H2 32
#define SLOPE 0.01f

static __device__ __forceinline__ float lrelu(float v) {
    return v > 0.0f ? v : SLOPE * v;
}

__global__ void k_init(float* __restrict__ deg, float* __restrict__ gsum,
                       float* __restrict__ gcnt) {
    int i = blockIdx.x * blockDim.x + threadIdx.x;
    if (i < N_NODES) deg[i] = 1.0f;                 // self-loop
    if (i < N_GRAPHS * H2) gsum[i] = 0.0f;
    if (i < N_GRAPHS) gcnt[i] = 0.0f;
}

__global__ void k_count(const int* __restrict__ dst, float* __restrict__ deg) {
    int e = blockIdx.x * blockDim.x + threadIdx.x;
    if (e < N_EDGES) atomicAdd(&deg[dst[e]], 1.0f);
}

__global__ void k_dis(const float* __restrict__ deg, float* __restrict__ dis) {
    int i = blockIdx.x * blockDim.x + threadIdx.x;
    if (i < N_NODES) dis[i] = rsqrtf(deg[i]);       // deg >= 1 always
}

// t1[n,f] = (x @ W1)[n,f] * dis[n];  acc1 initialized with self-loop term.
__global__ void k_t1(const float* __restrict__ x, const float* __restrict__ W1,
                     const float* __restrict__ dis,
                     float* __restrict__ t1, float* __restrict__ acc1) {
    int idx = blockIdx.x * blockDim.x + threadIdx.x;
    if (idx >= N_NODES * H1) return;
    int n = idx >> 6;          // /64
    int f = idx & 63;
    float s = 0.0f;
#pragma unroll
    for (int k = 0; k < IN_F; ++k)
        s += x[n * IN_F + k] * W1[k * H1 + f];
    s *= dis[n];
    t1[idx] = s;
    acc1[idx] = s;
}

// acc1[dst] += t1[src] for every edge; one wave (64 lanes) per edge.
__global__ void k_scatter1(const int* __restrict__ src, const int* __restrict__ dst,
                           const float* __restrict__ t1, float* __restrict__ acc1) {
    long long idx = (long long)blockIdx.x * blockDim.x + threadIdx.x;
    if (idx >= (long long)N_EDGES * H1) return;
    int e = (int)(idx >> 6);
    int f = (int)(idx & 63);
    int s = src[e], d = dst[e];
    atomicAdd(&acc1[(long long)d * H1 + f], t1[(long long)s * H1 + f]);
}

// layer 2: g1 = lrelu(acc1*dis + b1);  t2 = (g1 @ W2) * dis;  acc2 = t2.
__global__ void k_layer2(const float* __restrict__ acc1, const float* __restrict__ b1,
                         const float* __restrict__ W2, const float* __restrict__ dis,
                         float* __restrict__ t2, float* __restrict__ acc2) {
    int idx = blockIdx.x * blockDim.x + threadIdx.x;
    if (idx >= N_NODES * H2) return;
    int n = idx >> 5;          // /32
    int f2 = idx & 31;
    float dn = dis[n];
    float s = 0.0f;
#pragma unroll
    for (int k = 0; k < H1; ++k) {
        float a = acc1[n * H1 + k] * dn + b1[k];
        a = lrelu(a);
        s += a * W2[k * H2 + f2];
    }
    s *= dn;
    t2[idx] = s;
    acc2[idx] = s;
}

__global__ void k_scatter2(const int* __restrict__ src, const int* __restrict__ dst,
                           const float* __restrict__ t2, float* __restrict__ acc2) {
    long long idx = (long long)blockIdx.x * blockDim.x + threadIdx.x;
    if (idx >= (long long)N_EDGES * H2) return;
    int e = (int)(idx >> 5);
    int f = (int)(idx & 31);
    int s = src[e], d = dst[e];
    atomicAdd(&acc2[(long long)d * H2 + f], t2[(long long)s * H2 + f]);
}

// h2 = lrelu(acc2*dis + b2); accumulate per-graph sums + counts.
__global__ void k_pool(const float* __restrict__ acc2, const float* __restrict__ b2,
                       const float* __restrict__ dis, const int* __restrict__ batch,
                       float* __restrict__ gsum, float* __restrict__ gcnt) {
    int idx = blockIdx.x * blockDim.x + threadIdx.x;
    if (idx >= N_NODES * H2) return;
    int n = idx >> 5;
    int f = idx & 31;
    float v = acc2[idx] * dis[n] + b2[f];
    v = lrelu(v);
    int g = batch[n];
    atomicAdd(&gsum[g * H2 + f], v);
    if (f == 0) atomicAdd(&gcnt[g], 1.0f);
}

// out[g, t] = (gsum[g]/max(cnt,1)) @ Wlin + blin
__global__ void k_final(const float* __restrict__ gsum, const float* __restrict__ gcnt,
                        const float* __restrict__ Wlin, const float* __restrict__ blin,
                        float* __restrict__ out) {
    int idx = blockIdx.x * blockDim.x + threadIdx.x;
    if (idx >= N_GRAPHS * 2) return;
    int g = idx >> 1;
    int t = idx & 1;
    float inv = 1.0f / fmaxf(gcnt[g], 1.0f);
    float s = blin[t];
#pragma unroll
    for (int f = 0; f < H2; ++f)
        s += gsum[g * H2 + f] * inv * Wlin[f * 2 + t];
    out[idx] = s;
}

static inline int cdiv(long long a, int b) { return (int)((a + b - 1) / b); }

extern "C" void kernel_launch(void* const* d_in, const int* in_sizes, int n_in,
                              void* d_out, int out_size, void* d_ws, size_t ws_size,
                              hipStream_t stream) {
    const float* x    = (const float*)d_in[0];
    const int*   ei   = (const int*)d_in[1];          // [2, E]
    const int*   batch= (const int*)d_in[2];
    const float* W1   = (const float*)d_in[3];
    const float* b1   = (const float*)d_in[4];
    const float* W2   = (const float*)d_in[5];
    const float* b2   = (const float*)d_in[6];
    const float* Wlin = (const float*)d_in[7];
    const float* blin = (const float*)d_in[8];
    float* out = (float*)d_out;

    const int* src = ei;
    const int* dst = ei + N_EDGES;

    // workspace layout (floats)
    float* ws   = (float*)d_ws;
    float* deg  = ws;                         // N
    float* dis  = ws + N_NODES;               // N
    float* t1   = ws + 2LL * N_NODES;         // 64N   [2N, 66N)
    float* t2   = t1;                         // 32N   (reuses t1; t1 dead by then)
    float* acc2 = ws + 34LL * N_NODES;        // 32N   [34N, 66N)
    float* acc1 = ws + 66LL * N_NODES;        // 64N   [66N, 130N)
    float* gsum = ws + 130LL * N_NODES;       // G*32
    float* gcnt = gsum + (long long)N_GRAPHS * H2;

    const int B = 256;

    k_init<<<cdiv(N_NODES, B), B, 0, stream>>>(deg, gsum, gcnt);
    k_count<<<cdiv(N_EDGES, B), B, 0, stream>>>(dst, deg);
    k_dis<<<cdiv(N_NODES, B), B, 0, stream>>>(deg, dis);

    k_t1<<<cdiv((long long)N_NODES * H1, B), B, 0, stream>>>(x, W1, dis, t1, acc1);
    k_scatter1<<<cdiv((long long)N_EDGES * H1, B), B, 0, stream>>>(src, dst, t1, acc1);

    k_layer2<<<cdiv((long long)N_NODES * H2, B), B, 0, stream>>>(acc1, b1, W2, dis, t2, acc2);
    k_scatter2<<<cdiv((long long)N_EDGES * H2, B), B, 0, stream>>>(src, dst, t2, acc2);

    k_pool<<<cdiv((long long)N_NODES * H2, B), B, 0, stream>>>(acc2, b2, dis, batch, gsum, gcnt);
    k_final<<<cdiv(N_GRAPHS * 2, B), B, 0, stream>>>(gsum, gcnt, Wlin, blin, out);
}

// Round 2
// 1035.774 us; speedup vs baseline: 1.3125x; 1.3125x over previous
//
#include <hip/hip_runtime.h>

// GCN forward, CSR-gather formulation.
//   dis[n] = rsqrt(deg_in[n] + 1)                       (self-loop included)
//   layer1: aggx[n] = dis[n]*x[n] + sum_{s->n} dis[s]*x[s]        (6-wide!)
//           h1[n]   = lrelu(dis[n]*(aggx[n] @ W1) + b1)           [64]
//   layer2: t2[n]   = dis[n]*(h1[n] @ W2)                         [32]
//           agg2[n] = t2[n] + sum_{s->n} t2[s]
//           h2[n]   = lrelu(dis[n]*agg2[n] + b2)
//   pool:   gsum[batch[n]] += h2[n];  out = (gsum/cnt) @ Wlin + blin

#define N_NODES 100000
#define N_EDGES 3200000
#define N_GRAPHS 1024
#define IN_F 6
#define H1 64
#define H2 32
#define SLOPE 0.01f
#define SCAN_T 1024

static __device__ __forceinline__ float lrelu(float v) {
    return v > 0.0f ? v : SLOPE * v;
}

// histogram of incoming edges per node
__global__ void k_count(const int* __restrict__ dst, int* __restrict__ deg_i) {
    int e = blockIdx.x * blockDim.x + threadIdx.x;
    if (e < N_EDGES) atomicAdd(&deg_i[dst[e]], 1);
}

// single-block exclusive scan of deg_i -> offsets, cursor; also dis = rsqrt(deg+1)
__global__ void k_scan(const int* __restrict__ deg_i, int* __restrict__ offsets,
                       int* __restrict__ cursor, float* __restrict__ dis) {
    __shared__ int partial[SCAN_T];
    int tid = threadIdx.x;
    const int CH = (N_NODES + SCAN_T - 1) / SCAN_T;
    int begin = tid * CH;
    int end = begin + CH; if (end > N_NODES) end = N_NODES;
    int s = 0;
    for (int i = begin; i < end; ++i) s += deg_i[i];
    partial[tid] = s;
    __syncthreads();
    for (int off = 1; off < SCAN_T; off <<= 1) {
        int v = 0;
        if (tid >= off) v = partial[tid - off];
        __syncthreads();
        if (tid >= off) partial[tid] += v;
        __syncthreads();
    }
    int base = (tid == 0) ? 0 : partial[tid - 1];
    for (int i = begin; i < end; ++i) {
        offsets[i] = base;
        cursor[i] = base;
        int d = deg_i[i];
        dis[i] = rsqrtf((float)(d + 1));
        base += d;
    }
    if (tid == SCAN_T - 1) offsets[N_NODES] = base;   // == N_EDGES
}

// place src indices into CSR slots
__global__ void k_place(const int* __restrict__ src, const int* __restrict__ dst,
                        int* __restrict__ cursor, int* __restrict__ csr_src) {
    int e = blockIdx.x * blockDim.x + threadIdx.x;
    if (e >= N_EDGES) return;
    int slot = atomicAdd(&cursor[dst[e]], 1);
    csr_src[slot] = src[e];
}

// sx[n,:] = x[n,:] * dis[n]   (6 floats per node)
__global__ void k_sx(const float* __restrict__ x, const float* __restrict__ dis,
                     float* __restrict__ sx) {
    int idx = blockIdx.x * blockDim.x + threadIdx.x;
    if (idx >= N_NODES * IN_F) return;
    int n = idx / IN_F;
    sx[idx] = x[idx] * dis[n];
}

// aggx[n,f] = sx[n,f] + sum over incoming neighbors of sx[s,f]   (8 lanes/node, 6 used)
__global__ void k_gather1(const float* __restrict__ sx, const int* __restrict__ offsets,
                          const int* __restrict__ csr_src, float* __restrict__ aggx) {
    int idx = blockIdx.x * blockDim.x + threadIdx.x;
    if (idx >= N_NODES * 8) return;
    int n = idx >> 3;
    int f = idx & 7;
    if (f >= IN_F) return;
    float acc = sx[n * IN_F + f];
    int b = offsets[n], e = offsets[n + 1];
    for (int j = b; j < e; ++j) {
        int s = csr_src[j];
        acc += sx[s * IN_F + f];
    }
    aggx[n * IN_F + f] = acc;
}

// h1[n,f] = lrelu(dis[n] * (aggx[n,:] @ W1[:,f]) + b1[f])
__global__ void k_h1(const float* __restrict__ aggx, const float* __restrict__ W1,
                     const float* __restrict__ b1, const float* __restrict__ dis,
                     float* __restrict__ h1) {
    int idx = blockIdx.x * blockDim.x + threadIdx.x;
    if (idx >= N_NODES * H1) return;
    int n = idx >> 6;
    int f = idx & 63;
    float s = 0.0f;
#pragma unroll
    for (int k = 0; k < IN_F; ++k)
        s += aggx[n * IN_F + k] * W1[k * H1 + f];
    h1[idx] = lrelu(s * dis[n] + b1[f]);
}

// t2[n,f] = dis[n] * (h1[n,:] @ W2[:,f])
__global__ void k_t2(const float* __restrict__ h1, const float* __restrict__ W2,
                     const float* __restrict__ dis, float* __restrict__ t2) {
    int idx = blockIdx.x * blockDim.x + threadIdx.x;
    if (idx >= N_NODES * H2) return;
    int n = idx >> 5;
    int f = idx & 31;
    float s = 0.0f;
#pragma unroll 16
    for (int k = 0; k < H1; ++k)
        s += h1[n * H1 + k] * W2[k * H2 + f];
    t2[idx] = s * dis[n];
}

// agg2 gather + lrelu + fused mean-pool accumulation
__global__ void k_gather2(const float* __restrict__ t2, const int* __restrict__ offsets,
                          const int* __restrict__ csr_src, const float* __restrict__ dis,
                          const float* __restrict__ b2, const int* __restrict__ batch,
                          float* __restrict__ gsum, float* __restrict__ gcnt) {
    int idx = blockIdx.x * blockDim.x + threadIdx.x;
    if (idx >= N_NODES * H2) return;
    int n = idx >> 5;
    int f = idx & 31;
    float acc = t2[n * H2 + f];
    int b = offsets[n], e = offsets[n + 1];
    for (int j = b; j < e; ++j) {
        int s = csr_src[j];
        acc += t2[s * H2 + f];
    }
    float v = lrelu(acc * dis[n] + b2[f]);
    int g = batch[n];
    atomicAdd(&gsum[g * H2 + f], v);
    if (f == 0) atomicAdd(&gcnt[g], 1.0f);
}

__global__ void k_final(const float* __restrict__ gsum, const float* __restrict__ gcnt,
                        const float* __restrict__ Wlin, const float* __restrict__ blin,
                        float* __restrict__ out) {
    int idx = blockIdx.x * blockDim.x + threadIdx.x;
    if (idx >= N_GRAPHS * 2) return;
    int g = idx >> 1;
    int t = idx & 1;
    float inv = 1.0f / fmaxf(gcnt[g], 1.0f);
    float s = blin[t];
#pragma unroll
    for (int f = 0; f < H2; ++f)
        s += gsum[g * H2 + f] * inv * Wlin[f * 2 + t];
    out[idx] = s;
}

static inline int cdiv(long long a, int b) { return (int)((a + b - 1) / b); }

extern "C" void kernel_launch(void* const* d_in, const int* in_sizes, int n_in,
                              void* d_out, int out_size, void* d_ws, size_t ws_size,
                              hipStream_t stream) {
    const float* x    = (const float*)d_in[0];
    const int*   ei   = (const int*)d_in[1];          // [2, E] (int64 -> int32 by harness)
    const int*   batch= (const int*)d_in[2];
    const float* W1   = (const float*)d_in[3];
    const float* b1   = (const float*)d_in[4];
    const float* W2   = (const float*)d_in[5];
    const float* b2   = (const float*)d_in[6];
    const float* Wlin = (const float*)d_in[7];
    const float* blin = (const float*)d_in[8];
    float* out = (float*)d_out;

    const int* src = ei;
    const int* dst = ei + N_EDGES;

    // ---- workspace layout ----
    float* fws  = (float*)d_ws;
    float* dis  = fws;                                  // N
    float* sx   = fws + (long long)N_NODES;             // 6N
    float* aggx = sx  + 6LL * N_NODES;                  // 6N
    float* t2   = aggx + 6LL * N_NODES;                 // 32N
    float* h1   = t2  + 32LL * N_NODES;                 // 64N
    float* gsum = h1  + 64LL * N_NODES;                 // 32G
    float* gcnt = gsum + (long long)N_GRAPHS * H2;      // G
    int*  iws     = (int*)(gcnt + N_GRAPHS);
    int*  deg_i   = iws;                                // N
    int*  offsets = deg_i + N_NODES;                    // N+1
    int*  cursor  = offsets + N_NODES + 1;              // N
    int*  csr_src = cursor + N_NODES;                   // E

    const int B = 256;

    hipMemsetAsync(deg_i, 0, sizeof(int) * N_NODES, stream);
    hipMemsetAsync(gsum, 0, sizeof(float) * (N_GRAPHS * H2 + N_GRAPHS), stream);

    k_count<<<cdiv(N_EDGES, B), B, 0, stream>>>(dst, deg_i);
    k_scan<<<1, SCAN_T, 0, stream>>>(deg_i, offsets, cursor, dis);
    k_place<<<cdiv(N_EDGES, B), B, 0, stream>>>(src, dst, cursor, csr_src);

    k_sx<<<cdiv((long long)N_NODES * IN_F, B), B, 0, stream>>>(x, dis, sx);
    k_gather1<<<cdiv((long long)N_NODES * 8, B), B, 0, stream>>>(sx, offsets, csr_src, aggx);
    k_h1<<<cdiv((long long)N_NODES * H1, B), B, 0, stream>>>(aggx, W1, b1, dis, h1);
    k_t2<<<cdiv((long long)N_NODES * H2, B), B, 0, stream>>>(h1, W2, dis, t2);
    k_gather2<<<cdiv((long long)N_NODES * H2, B), B, 0, stream>>>(t2, offsets, csr_src, dis,
                                                                  b2, batch, gsum, gcnt);
    k_final<<<cdiv(N_GRAPHS * 2, B), B, 0, stream>>>(gsum, gcnt, Wlin, blin, out);
}

// Round 3
// 589.182 us; speedup vs baseline: 2.3074x; 1.7580x over previous
//
#include <hip/hip_runtime.h>

// GCN forward, CSR-gather formulation, round 3.
//   dis[n] = rsqrt(deg_in[n] + 1)
//   layer1: aggx[n] = dis[n]*x[n] + sum_{s->n} dis[s]*x[s]   (6-wide, linearity trick)
//           h1[n]   = lrelu(dis[n]*(aggx[n] @ W1) + b1)      [64]  (kept in LDS only)
//   layer2: t2[n]   = dis[n]*(h1[n] @ W2)                    [32]
//           h2[n]   = lrelu(dis[n]*(t2[n] + sum t2[s]) + b2)
//   pool:   gsum[batch[n]] += h2[n];  out = (gsum/cnt) @ Wlin + blin

#define N_NODES 100000
#define N_EDGES 3200000
#define N_GRAPHS 1024
#define IN_F 6
#define H1 64
#define H2 32
#define SLOPE 0.01f

#define SCAN_BLK 1024
#define SCAN_NB ((N_NODES + SCAN_BLK - 1) / SCAN_BLK)   // 98
#define NXCD 8
#define NODES_PER_XCD (N_NODES / NXCD)                  // 12500

static __device__ __forceinline__ float lrelu(float v) {
    return v > 0.0f ? v : SLOPE * v;
}

// histogram of incoming edges per node (int4-vectorized, grid-stride)
__global__ void k_count(const int* __restrict__ dst, int* __restrict__ deg_i) {
    int t = blockIdx.x * blockDim.x + threadIdx.x;
    int stride = gridDim.x * blockDim.x;
    const int4* d4 = (const int4*)dst;
    for (int i = t; i < N_EDGES / 4; i += stride) {
        int4 v = d4[i];
        atomicAdd(&deg_i[v.x], 1);
        atomicAdd(&deg_i[v.y], 1);
        atomicAdd(&deg_i[v.z], 1);
        atomicAdd(&deg_i[v.w], 1);
    }
}

// per-block sums of deg_i (SCAN_NB blocks x 1024 threads)
__global__ void k_bsum(const int* __restrict__ deg_i, int* __restrict__ bsum) {
    __shared__ int red[SCAN_BLK];
    int tid = threadIdx.x;
    int i = blockIdx.x * SCAN_BLK + tid;
    red[tid] = (i < N_NODES) ? deg_i[i] : 0;
    __syncthreads();
    for (int s = SCAN_BLK / 2; s > 0; s >>= 1) {
        if (tid < s) red[tid] += red[tid + s];
        __syncthreads();
    }
    if (tid == 0) bsum[blockIdx.x] = red[0];
}

// exclusive scan of the SCAN_NB block sums (1 block, 128 threads)
__global__ void k_bscan(const int* __restrict__ bsum, int* __restrict__ bscan) {
    __shared__ int sc[128];
    int tid = threadIdx.x;
    int v = (tid < SCAN_NB) ? bsum[tid] : 0;
    sc[tid] = v;
    __syncthreads();
    for (int off = 1; off < 128; off <<= 1) {
        int t = 0;
        if (tid >= off) t = sc[tid - off];
        __syncthreads();
        if (tid >= off) sc[tid] += t;
        __syncthreads();
    }
    if (tid < SCAN_NB) bscan[tid] = sc[tid] - v;   // exclusive
}

// per-block scan -> offsets/cursor; also dis = rsqrt(deg+1) and sx = x*dis
__global__ void k_csr(const int* __restrict__ deg_i, const int* __restrict__ bscan,
                      const float* __restrict__ x,
                      int* __restrict__ offsets, int* __restrict__ cursor,
                      float* __restrict__ dis, float* __restrict__ sx) {
    __shared__ int sc[SCAN_BLK];
    int tid = threadIdx.x;
    int i = blockIdx.x * SCAN_BLK + tid;
    int v = (i < N_NODES) ? deg_i[i] : 0;
    sc[tid] = v;
    __syncthreads();
    for (int off = 1; off < SCAN_BLK; off <<= 1) {
        int t = 0;
        if (tid >= off) t = sc[tid - off];
        __syncthreads();
        if (tid >= off) sc[tid] += t;
        __syncthreads();
    }
    int base = bscan[blockIdx.x];
    if (i < N_NODES) {
        int excl = base + sc[tid] - v;
        offsets[i] = excl;
        cursor[i] = excl;
        float dn = rsqrtf((float)(v + 1));
        dis[i] = dn;
#pragma unroll
        for (int j = 0; j < IN_F; ++j)
            sx[i * IN_F + j] = x[i * IN_F + j] * dn;
        if (i == N_NODES - 1) offsets[N_NODES] = base + sc[tid];
    }
}

// XCD-partitioned CSR placement: block group (blockIdx & 7) handles one
// 1/8th dst range so csr_src/cursor cache lines stay single-XCD and merge
// in the local L2 before writeback (fixes 16x HBM write amplification).
__global__ void k_place(const int* __restrict__ src, const int* __restrict__ dst,
                        int* __restrict__ cursor, int* __restrict__ csr_src) {
    int xcd = blockIdx.x & (NXCD - 1);
    int lo = xcd * NODES_PER_XCD;
    int hi = lo + NODES_PER_XCD;          // N_NODES divisible by 8
    int grp = blockIdx.x >> 3;
    int ngrp = gridDim.x >> 3;
    int t = grp * blockDim.x + threadIdx.x;
    int stride = ngrp * blockDim.x;
    const int4* d4 = (const int4*)dst;
    const int4* s4 = (const int4*)src;
    for (int i = t; i < N_EDGES / 4; i += stride) {
        int4 dv = d4[i];
        int4 sv = s4[i];
        if (dv.x >= lo && dv.x < hi) csr_src[atomicAdd(&cursor[dv.x], 1)] = sv.x;
        if (dv.y >= lo && dv.y < hi) csr_src[atomicAdd(&cursor[dv.y], 1)] = sv.y;
        if (dv.z >= lo && dv.z < hi) csr_src[atomicAdd(&cursor[dv.z], 1)] = sv.z;
        if (dv.w >= lo && dv.w < hi) csr_src[atomicAdd(&cursor[dv.w], 1)] = sv.w;
    }
}

// aggx[n,f] = sx[n,f] + sum over incoming neighbors (8 lanes/node, 6 used)
__global__ void k_gather1(const float* __restrict__ sx, const int* __restrict__ offsets,
                          const int* __restrict__ csr_src, float* __restrict__ aggx) {
    int idx = blockIdx.x * blockDim.x + threadIdx.x;
    if (idx >= N_NODES * 8) return;
    int n = idx >> 3;
    int f = idx & 7;
    if (f >= IN_F) return;
    float acc = sx[n * IN_F + f];
    int b = offsets[n], e = offsets[n + 1];
    for (int j = b; j < e; ++j) {
        int s = csr_src[j];
        acc += sx[s * IN_F + f];
    }
    aggx[n * IN_F + f] = acc;
}

// fused: h1 = lrelu(dis*(aggx@W1)+b1) (LDS only), t2 = dis*(h1@W2)
// 256 threads = 8 nodes x 32 lanes
__global__ void k_h1t2(const float* __restrict__ aggx, const float* __restrict__ W1,
                       const float* __restrict__ b1, const float* __restrict__ W2,
                       const float* __restrict__ dis, float* __restrict__ t2) {
    __shared__ float sW1[IN_F * H1];
    __shared__ float sb1[H1];
    __shared__ float sW2[H1 * H2];
    __shared__ float sh1[8][H1];
    int tid = threadIdx.x;
    for (int i = tid; i < IN_F * H1; i += 256) sW1[i] = W1[i];
    if (tid < H1) sb1[tid] = b1[tid];
    for (int i = tid; i < H1 * H2; i += 256) sW2[i] = W2[i];
    int loc = tid >> 5;
    int lane = tid & 31;
    int n = blockIdx.x * 8 + loc;
    bool ok = n < N_NODES;
    float a[IN_F];
    float dn = 0.0f;
    if (ok) {
        dn = dis[n];
#pragma unroll
        for (int j = 0; j < IN_F; ++j) a[j] = aggx[n * IN_F + j];
    }
    __syncthreads();
    if (ok) {
#pragma unroll
        for (int kk = 0; kk < 2; ++kk) {
            int k = lane + kk * 32;
            float s = 0.0f;
#pragma unroll
            for (int j = 0; j < IN_F; ++j) s += a[j] * sW1[j * H1 + k];
            sh1[loc][k] = lrelu(s * dn + sb1[k]);
        }
    }
    __syncthreads();
    if (ok) {
        float s = 0.0f;
#pragma unroll
        for (int k = 0; k < H1; ++k) s += sh1[loc][k] * sW2[k * H2 + lane];
        t2[n * H2 + lane] = s * dn;
    }
}

// agg2 gather + lrelu + fused mean-pool accumulation (32 lanes/node)
__global__ void k_gather2(const float* __restrict__ t2, const int* __restrict__ offsets,
                          const int* __restrict__ csr_src, const float* __restrict__ dis,
                          const float* __restrict__ b2, const int* __restrict__ batch,
                          float* __restrict__ gsum, float* __restrict__ gcnt) {
    int idx = blockIdx.x * blockDim.x + threadIdx.x;
    if (idx >= N_NODES * H2) return;
    int n = idx >> 5;
    int f = idx & 31;
    float acc = t2[n * H2 + f];
    int b = offsets[n], e = offsets[n + 1];
    for (int j = b; j < e; ++j) {
        int s = csr_src[j];
        acc += t2[s * H2 + f];
    }
    float v = lrelu(acc * dis[n] + b2[f]);
    int g = batch[n];
    atomicAdd(&gsum[g * H2 + f], v);
    if (f == 0) atomicAdd(&gcnt[g], 1.0f);
}

__global__ void k_final(const float* __restrict__ gsum, const float* __restrict__ gcnt,
                        const float* __restrict__ Wlin, const float* __restrict__ blin,
                        float* __restrict__ out) {
    int idx = blockIdx.x * blockDim.x + threadIdx.x;
    if (idx >= N_GRAPHS * 2) return;
    int g = idx >> 1;
    int t = idx & 1;
    float inv = 1.0f / fmaxf(gcnt[g], 1.0f);
    float s = blin[t];
#pragma unroll
    for (int f = 0; f < H2; ++f)
        s += gsum[g * H2 + f] * inv * Wlin[f * 2 + t];
    out[idx] = s;
}

static inline int cdiv(long long a, int b) { return (int)((a + b - 1) / b); }

extern "C" void kernel_launch(void* const* d_in, const int* in_sizes, int n_in,
                              void* d_out, int out_size, void* d_ws, size_t ws_size,
                              hipStream_t stream) {
    const float* x    = (const float*)d_in[0];
    const int*   ei   = (const int*)d_in[1];
    const int*   batch= (const int*)d_in[2];
    const float* W1   = (const float*)d_in[3];
    const float* b1   = (const float*)d_in[4];
    const float* W2   = (const float*)d_in[5];
    const float* b2   = (const float*)d_in[6];
    const float* Wlin = (const float*)d_in[7];
    const float* blin = (const float*)d_in[8];
    float* out = (float*)d_out;

    const int* src = ei;
    const int* dst = ei + N_EDGES;

    // ---- workspace layout ----
    float* fws  = (float*)d_ws;
    float* dis  = fws;                                  // N
    float* sx   = fws + (long long)N_NODES;             // 6N
    float* aggx = sx  + 6LL * N_NODES;                  // 6N
    float* t2   = aggx + 6LL * N_NODES;                 // 32N
    float* gsum = t2  + 32LL * N_NODES;                 // 32G
    float* gcnt = gsum + (long long)N_GRAPHS * H2;      // G
    int*  iws     = (int*)(gcnt + N_GRAPHS);
    int*  deg_i   = iws;                                // N
    int*  offsets = deg_i + N_NODES;                    // N+1
    int*  cursor  = offsets + N_NODES + 1;              // N
    int*  bsum    = cursor + N_NODES;                   // 128
    int*  bscan   = bsum + 128;                         // 128
    int*  csr_src = bscan + 128;                        // E

    const int B = 256;

    hipMemsetAsync(deg_i, 0, sizeof(int) * N_NODES, stream);
    hipMemsetAsync(gsum, 0, sizeof(float) * (N_GRAPHS * H2 + N_GRAPHS), stream);

    k_count<<<2048, B, 0, stream>>>(dst, deg_i);
    k_bsum<<<SCAN_NB, SCAN_BLK, 0, stream>>>(deg_i, bsum);
    k_bscan<<<1, 128, 0, stream>>>(bsum, bscan);
    k_csr<<<SCAN_NB, SCAN_BLK, 0, stream>>>(deg_i, bscan, x, offsets, cursor, dis, sx);
    k_place<<<2048, B, 0, stream>>>(src, dst, cursor, csr_src);

    k_gather1<<<cdiv((long long)N_NODES * 8, B), B, 0, stream>>>(sx, offsets, csr_src, aggx);
    k_h1t2<<<cdiv(N_NODES, 8), B, 0, stream>>>(aggx, W1, b1, W2, dis, t2);
    k_gather2<<<cdiv((long long)N_NODES * H2, B), B, 0, stream>>>(t2, offsets, csr_src, dis,
                                                                  b2, batch, gsum, gcnt);
    k_final<<<cdiv(N_GRAPHS * 2, B), B, 0, stream>>>(gsum, gcnt, Wlin, blin, out);
}

// Round 4
// 511.801 us; speedup vs baseline: 2.6562x; 1.1512x over previous
//
#include <hip/hip_runtime.h>

// GCN forward, CSR-gather formulation, round 4 (MLP-unrolled gathers).
//   dis[n] = rsqrt(deg_in[n] + 1)
//   layer1: aggx[n] = dis[n]*x[n] + sum_{s->n} dis[s]*x[s]   (6-wide, padded to 8)
//           h1[n]   = lrelu(dis[n]*(aggx[n] @ W1) + b1)      [64]  (LDS only)
//   layer2: t2[n]   = dis[n]*(h1[n] @ W2)                    [32]
//           h2[n]   = lrelu(dis[n]*(t2[n] + sum t2[s]) + b2)
//   pool:   gsum[batch[n]] += h2[n];  out = (gsum/cnt) @ Wlin + blin

#define N_NODES 100000
#define N_EDGES 3200000
#define N_GRAPHS 1024
#define IN_F 6
#define SXS 8            // padded row stride for sx/aggx
#define H1 64
#define H2 32
#define SLOPE 0.01f

#define SCAN_BLK 1024
#define SCAN_NB ((N_NODES + SCAN_BLK - 1) / SCAN_BLK)   // 98
#define NXCD 8
#define NODES_PER_XCD (N_NODES / NXCD)                  // 12500

static __device__ __forceinline__ float lrelu(float v) {
    return v > 0.0f ? v : SLOPE * v;
}

// histogram of incoming edges per node (int4-vectorized, grid-stride)
__global__ void k_count(const int* __restrict__ dst, int* __restrict__ deg_i) {
    int t = blockIdx.x * blockDim.x + threadIdx.x;
    int stride = gridDim.x * blockDim.x;
    const int4* d4 = (const int4*)dst;
    for (int i = t; i < N_EDGES / 4; i += stride) {
        int4 v = d4[i];
        atomicAdd(&deg_i[v.x], 1);
        atomicAdd(&deg_i[v.y], 1);
        atomicAdd(&deg_i[v.z], 1);
        atomicAdd(&deg_i[v.w], 1);
    }
}

// per-block sums of deg_i
__global__ void k_bsum(const int* __restrict__ deg_i, int* __restrict__ bsum) {
    __shared__ int red[SCAN_BLK];
    int tid = threadIdx.x;
    int i = blockIdx.x * SCAN_BLK + tid;
    red[tid] = (i < N_NODES) ? deg_i[i] : 0;
    __syncthreads();
    for (int s = SCAN_BLK / 2; s > 0; s >>= 1) {
        if (tid < s) red[tid] += red[tid + s];
        __syncthreads();
    }
    if (tid == 0) bsum[blockIdx.x] = red[0];
}

// exclusive scan of block sums (1 block, 128 threads)
__global__ void k_bscan(const int* __restrict__ bsum, int* __restrict__ bscan) {
    __shared__ int sc[128];
    int tid = threadIdx.x;
    int v = (tid < SCAN_NB) ? bsum[tid] : 0;
    sc[tid] = v;
    __syncthreads();
    for (int off = 1; off < 128; off <<= 1) {
        int t = 0;
        if (tid >= off) t = sc[tid - off];
        __syncthreads();
        if (tid >= off) sc[tid] += t;
        __syncthreads();
    }
    if (tid < SCAN_NB) bscan[tid] = sc[tid] - v;   // exclusive
}

// per-block scan -> offsets/cursor; dis = rsqrt(deg+1); sx = x*dis (stride 8, zero-pad)
__global__ void k_csr(const int* __restrict__ deg_i, const int* __restrict__ bscan,
                      const float* __restrict__ x,
                      int* __restrict__ offsets, int* __restrict__ cursor,
                      float* __restrict__ dis, float* __restrict__ sx) {
    __shared__ int sc[SCAN_BLK];
    int tid = threadIdx.x;
    int i = blockIdx.x * SCAN_BLK + tid;
    int v = (i < N_NODES) ? deg_i[i] : 0;
    sc[tid] = v;
    __syncthreads();
    for (int off = 1; off < SCAN_BLK; off <<= 1) {
        int t = 0;
        if (tid >= off) t = sc[tid - off];
        __syncthreads();
        if (tid >= off) sc[tid] += t;
        __syncthreads();
    }
    int base = bscan[blockIdx.x];
    if (i < N_NODES) {
        int excl = base + sc[tid] - v;
        offsets[i] = excl;
        cursor[i] = excl;
        float dn = rsqrtf((float)(v + 1));
        dis[i] = dn;
#pragma unroll
        for (int j = 0; j < IN_F; ++j)
            sx[i * SXS + j] = x[i * IN_F + j] * dn;
        sx[i * SXS + 6] = 0.0f;
        sx[i * SXS + 7] = 0.0f;
        if (i == N_NODES - 1) offsets[N_NODES] = base + sc[tid];
    }
}

// XCD-partitioned CSR placement (keeps csr/cursor lines single-XCD).
__global__ void k_place(const int* __restrict__ src, const int* __restrict__ dst,
                        int* __restrict__ cursor, int* __restrict__ csr_src) {
    int xcd = blockIdx.x & (NXCD - 1);
    int lo = xcd * NODES_PER_XCD;
    int hi = lo + NODES_PER_XCD;
    int grp = blockIdx.x >> 3;
    int ngrp = gridDim.x >> 3;
    int t = grp * blockDim.x + threadIdx.x;
    int stride = ngrp * blockDim.x;
    const int4* d4 = (const int4*)dst;
    const int4* s4 = (const int4*)src;
    for (int i = t; i < N_EDGES / 4; i += stride) {
        int4 dv = d4[i];
        int4 sv = s4[i];
        if (dv.x >= lo && dv.x < hi) csr_src[atomicAdd(&cursor[dv.x], 1)] = sv.x;
        if (dv.y >= lo && dv.y < hi) csr_src[atomicAdd(&cursor[dv.y], 1)] = sv.y;
        if (dv.z >= lo && dv.z < hi) csr_src[atomicAdd(&cursor[dv.z], 1)] = sv.z;
        if (dv.w >= lo && dv.w < hi) csr_src[atomicAdd(&cursor[dv.w], 1)] = sv.w;
    }
}

// aggx[n,f] = sx[n,f] + sum over incoming neighbors; 8 lanes/node, unroll x8 for MLP
__global__ void k_gather1(const float* __restrict__ sx, const int* __restrict__ offsets,
                          const int* __restrict__ csr_src, float* __restrict__ aggx) {
    int idx = blockIdx.x * blockDim.x + threadIdx.x;
    if (idx >= N_NODES * 8) return;
    int n = idx >> 3;
    int f = idx & 7;
    float acc = sx[(n << 3) + f];
    int b = offsets[n], e = offsets[n + 1];
    int j = b;
    for (; j + 8 <= e; j += 8) {
        int s0 = csr_src[j + 0], s1 = csr_src[j + 1];
        int s2 = csr_src[j + 2], s3 = csr_src[j + 3];
        int s4 = csr_src[j + 4], s5 = csr_src[j + 5];
        int s6 = csr_src[j + 6], s7 = csr_src[j + 7];
        float v0 = sx[(s0 << 3) + f], v1 = sx[(s1 << 3) + f];
        float v2 = sx[(s2 << 3) + f], v3 = sx[(s3 << 3) + f];
        float v4 = sx[(s4 << 3) + f], v5 = sx[(s5 << 3) + f];
        float v6 = sx[(s6 << 3) + f], v7 = sx[(s7 << 3) + f];
        acc += ((v0 + v1) + (v2 + v3)) + ((v4 + v5) + (v6 + v7));
    }
    for (; j < e; ++j)
        acc += sx[(csr_src[j] << 3) + f];
    aggx[(n << 3) + f] = acc;
}

// fused: h1 = lrelu(dis*(aggx@W1)+b1) (LDS only), t2 = dis*(h1@W2)
__global__ void k_h1t2(const float* __restrict__ aggx, const float* __restrict__ W1,
                       const float* __restrict__ b1, const float* __restrict__ W2,
                       const float* __restrict__ dis, float* __restrict__ t2) {
    __shared__ float sW1[IN_F * H1];
    __shared__ float sb1[H1];
    __shared__ float sW2[H1 * H2];
    __shared__ float sh1[8][H1];
    int tid = threadIdx.x;
    for (int i = tid; i < IN_F * H1; i += 256) sW1[i] = W1[i];
    if (tid < H1) sb1[tid] = b1[tid];
    for (int i = tid; i < H1 * H2; i += 256) sW2[i] = W2[i];
    int loc = tid >> 5;
    int lane = tid & 31;
    int n = blockIdx.x * 8 + loc;
    bool ok = n < N_NODES;
    float a[IN_F];
    float dn = 0.0f;
    if (ok) {
        dn = dis[n];
#pragma unroll
        for (int j = 0; j < IN_F; ++j) a[j] = aggx[n * SXS + j];
    }
    __syncthreads();
    if (ok) {
#pragma unroll
        for (int kk = 0; kk < 2; ++kk) {
            int k = lane + kk * 32;
            float s = 0.0f;
#pragma unroll
            for (int j = 0; j < IN_F; ++j) s += a[j] * sW1[j * H1 + k];
            sh1[loc][k] = lrelu(s * dn + sb1[k]);
        }
    }
    __syncthreads();
    if (ok) {
        float s = 0.0f;
#pragma unroll
        for (int k = 0; k < H1; ++k) s += sh1[loc][k] * sW2[k * H2 + lane];
        t2[n * H2 + lane] = s * dn;
    }
}

// agg2 gather (unroll x8) + lrelu + fused mean-pool accumulation (32 lanes/node)
__global__ void k_gather2(const float* __restrict__ t2, const int* __restrict__ offsets,
                          const int* __restrict__ csr_src, const float* __restrict__ dis,
                          const float* __restrict__ b2, const int* __restrict__ batch,
                          float* __restrict__ gsum, float* __restrict__ gcnt) {
    int idx = blockIdx.x * blockDim.x + threadIdx.x;
    if (idx >= N_NODES * H2) return;
    int n = idx >> 5;
    int f = idx & 31;
    float acc = t2[(n << 5) + f];
    int b = offsets[n], e = offsets[n + 1];
    int j = b;
    for (; j + 8 <= e; j += 8) {
        int s0 = csr_src[j + 0], s1 = csr_src[j + 1];
        int s2 = csr_src[j + 2], s3 = csr_src[j + 3];
        int s4 = csr_src[j + 4], s5 = csr_src[j + 5];
        int s6 = csr_src[j + 6], s7 = csr_src[j + 7];
        float v0 = t2[(s0 << 5) + f], v1 = t2[(s1 << 5) + f];
        float v2 = t2[(s2 << 5) + f], v3 = t2[(s3 << 5) + f];
        float v4 = t2[(s4 << 5) + f], v5 = t2[(s5 << 5) + f];
        float v6 = t2[(s6 << 5) + f], v7 = t2[(s7 << 5) + f];
        acc += ((v0 + v1) + (v2 + v3)) + ((v4 + v5) + (v6 + v7));
    }
    for (; j < e; ++j)
        acc += t2[(csr_src[j] << 5) + f];
    float v = lrelu(acc * dis[n] + b2[f]);
    int g = batch[n];
    atomicAdd(&gsum[g * H2 + f], v);
    if (f == 0) atomicAdd(&gcnt[g], 1.0f);
}

__global__ void k_final(const float* __restrict__ gsum, const float* __restrict__ gcnt,
                        const float* __restrict__ Wlin, const float* __restrict__ blin,
                        float* __restrict__ out) {
    int idx = blockIdx.x * blockDim.x + threadIdx.x;
    if (idx >= N_GRAPHS * 2) return;
    int g = idx >> 1;
    int t = idx & 1;
    float inv = 1.0f / fmaxf(gcnt[g], 1.0f);
    float s = blin[t];
#pragma unroll
    for (int f = 0; f < H2; ++f)
        s += gsum[g * H2 + f] * inv * Wlin[f * 2 + t];
    out[idx] = s;
}

static inline int cdiv(long long a, int b) { return (int)((a + b - 1) / b); }

extern "C" void kernel_launch(void* const* d_in, const int* in_sizes, int n_in,
                              void* d_out, int out_size, void* d_ws, size_t ws_size,
                              hipStream_t stream) {
    const float* x    = (const float*)d_in[0];
    const int*   ei   = (const int*)d_in[1];
    const int*   batch= (const int*)d_in[2];
    const float* W1   = (const float*)d_in[3];
    const float* b1   = (const float*)d_in[4];
    const float* W2   = (const float*)d_in[5];
    const float* b2   = (const float*)d_in[6];
    const float* Wlin = (const float*)d_in[7];
    const float* blin = (const float*)d_in[8];
    float* out = (float*)d_out;

    const int* src = ei;
    const int* dst = ei + N_EDGES;

    // ---- workspace layout (t2 first for 128B row alignment) ----
    float* fws  = (float*)d_ws;
    float* t2   = fws;                                  // 32N (128B-aligned rows)
    float* dis  = t2  + 32LL * N_NODES;                 // N
    float* sx   = dis + (long long)N_NODES;             // 8N
    float* aggx = sx  + 8LL * N_NODES;                  // 8N
    float* gsum = aggx + 8LL * N_NODES;                 // 32G
    float* gcnt = gsum + (long long)N_GRAPHS * H2;      // G
    int*  iws     = (int*)(gcnt + N_GRAPHS);
    int*  deg_i   = iws;                                // N
    int*  offsets = deg_i + N_NODES;                    // N+1
    int*  cursor  = offsets + N_NODES + 1;              // N
    int*  bsum    = cursor + N_NODES;                   // 128
    int*  bscan   = bsum + 128;                         // 128
    int*  csr_src = bscan + 128;                        // E

    const int B = 256;

    hipMemsetAsync(deg_i, 0, sizeof(int) * N_NODES, stream);
    hipMemsetAsync(gsum, 0, sizeof(float) * (N_GRAPHS * H2 + N_GRAPHS), stream);

    k_count<<<2048, B, 0, stream>>>(dst, deg_i);
    k_bsum<<<SCAN_NB, SCAN_BLK, 0, stream>>>(deg_i, bsum);
    k_bscan<<<1, 128, 0, stream>>>(bsum, bscan);
    k_csr<<<SCAN_NB, SCAN_BLK, 0, stream>>>(deg_i, bscan, x, offsets, cursor, dis, sx);
    k_place<<<2048, B, 0, stream>>>(src, dst, cursor, csr_src);

    k_gather1<<<cdiv((long long)N_NODES * 8, B), B, 0, stream>>>(sx, offsets, csr_src, aggx);
    k_h1t2<<<cdiv(N_NODES, 8), B, 0, stream>>>(aggx, W1, b1, W2, dis, t2);
    k_gather2<<<cdiv((long long)N_NODES * H2, B), B, 0, stream>>>(t2, offsets, csr_src, dis,
                                                                  b2, batch, gsum, gcnt);
    k_final<<<cdiv(N_GRAPHS * 2, B), B, 0, stream>>>(gsum, gcnt, Wlin, blin, out);
}

// Round 5
// 405.260 us; speedup vs baseline: 3.3545x; 1.2629x over previous
//
#include <hip/hip_runtime.h>

// GCN forward, CSR-gather formulation, round 5.
// fp16 gather tables (t2, sx), 8-aligned padded adjacency lists,
// LDS-deduplicated pool atomics, XCD-partitioned histogram/placement.

#define N_NODES 100000
#define N_EDGES 3200000
#define N_GRAPHS 1024
#define IN_F 6
#define SXS 8            // padded row stride for sx/aggx
#define H1 64
#define H2 32
#define SLOPE 0.01f

#define SCAN_BLK 1024
#define SCAN_NB ((N_NODES + SCAN_BLK - 1) / SCAN_BLK)   // 98
#define NXCD 8
#define NODES_PER_XCD (N_NODES / NXCD)                  // 12500
#define CSR_CAP 4000000                                 // >= E + 7N

typedef _Float16 f16;

static __device__ __forceinline__ float lrelu(float v) {
    return v > 0.0f ? v : SLOPE * v;
}

// XCD-partitioned histogram of incoming edges per node
__global__ void k_count(const int* __restrict__ dst, int* __restrict__ deg_i) {
    int xcd = blockIdx.x & (NXCD - 1);
    int lo = xcd * NODES_PER_XCD;
    int hi = lo + NODES_PER_XCD;
    int grp = blockIdx.x >> 3;
    int ngrp = gridDim.x >> 3;
    int t = grp * blockDim.x + threadIdx.x;
    int stride = ngrp * blockDim.x;
    const int4* d4 = (const int4*)dst;
    for (int i = t; i < N_EDGES / 4; i += stride) {
        int4 v = d4[i];
        if (v.x >= lo && v.x < hi) atomicAdd(&deg_i[v.x], 1);
        if (v.y >= lo && v.y < hi) atomicAdd(&deg_i[v.y], 1);
        if (v.z >= lo && v.z < hi) atomicAdd(&deg_i[v.z], 1);
        if (v.w >= lo && v.w < hi) atomicAdd(&deg_i[v.w], 1);
    }
}

// per-block sums of 8-padded degrees
__global__ void k_bsum(const int* __restrict__ deg_i, int* __restrict__ bsum) {
    __shared__ int red[SCAN_BLK];
    int tid = threadIdx.x;
    int i = blockIdx.x * SCAN_BLK + tid;
    red[tid] = (i < N_NODES) ? ((deg_i[i] + 7) & ~7) : 0;
    __syncthreads();
    for (int s = SCAN_BLK / 2; s > 0; s >>= 1) {
        if (tid < s) red[tid] += red[tid + s];
        __syncthreads();
    }
    if (tid == 0) bsum[blockIdx.x] = red[0];
}

// exclusive scan of block sums (1 block, 128 threads)
__global__ void k_bscan(const int* __restrict__ bsum, int* __restrict__ bscan) {
    __shared__ int sc[128];
    int tid = threadIdx.x;
    int v = (tid < SCAN_NB) ? bsum[tid] : 0;
    sc[tid] = v;
    __syncthreads();
    for (int off = 1; off < 128; off <<= 1) {
        int t = 0;
        if (tid >= off) t = sc[tid - off];
        __syncthreads();
        if (tid >= off) sc[tid] += t;
        __syncthreads();
    }
    if (tid < SCAN_NB) bscan[tid] = sc[tid] - v;   // exclusive
}

// per-block scan of padded degrees -> offsets/cursor; dis = rsqrt(deg+1);
// sx = x*dis in fp16 (stride 8, zero-pad)
__global__ void k_csr(const int* __restrict__ deg_i, const int* __restrict__ bscan,
                      const float* __restrict__ x,
                      int* __restrict__ offsets, int* __restrict__ cursor,
                      float* __restrict__ dis, f16* __restrict__ sx) {
    __shared__ int sc[SCAN_BLK];
    int tid = threadIdx.x;
    int i = blockIdx.x * SCAN_BLK + tid;
    int dv = (i < N_NODES) ? deg_i[i] : 0;
    int v = (i < N_NODES) ? ((dv + 7) & ~7) : 0;
    sc[tid] = v;
    __syncthreads();
    for (int off = 1; off < SCAN_BLK; off <<= 1) {
        int t = 0;
        if (tid >= off) t = sc[tid - off];
        __syncthreads();
        if (tid >= off) sc[tid] += t;
        __syncthreads();
    }
    int base = bscan[blockIdx.x];
    if (i < N_NODES) {
        int excl = base + sc[tid] - v;
        offsets[i] = excl;
        cursor[i] = excl;
        float dn = rsqrtf((float)(dv + 1));
        dis[i] = dn;
#pragma unroll
        for (int j = 0; j < IN_F; ++j)
            sx[i * SXS + j] = (f16)(x[i * IN_F + j] * dn);
        sx[i * SXS + 6] = (f16)0.0f;
        sx[i * SXS + 7] = (f16)0.0f;
        if (i == N_NODES - 1) offsets[N_NODES] = base + sc[tid];
    }
}

// XCD-partitioned CSR placement
__global__ void k_place(const int* __restrict__ src, const int* __restrict__ dst,
                        int* __restrict__ cursor, int* __restrict__ csr_src) {
    int xcd = blockIdx.x & (NXCD - 1);
    int lo = xcd * NODES_PER_XCD;
    int hi = lo + NODES_PER_XCD;
    int grp = blockIdx.x >> 3;
    int ngrp = gridDim.x >> 3;
    int t = grp * blockDim.x + threadIdx.x;
    int stride = ngrp * blockDim.x;
    const int4* d4 = (const int4*)dst;
    const int4* s4 = (const int4*)src;
    for (int i = t; i < N_EDGES / 4; i += stride) {
        int4 dv = d4[i];
        int4 sv = s4[i];
        if (dv.x >= lo && dv.x < hi) csr_src[atomicAdd(&cursor[dv.x], 1)] = sv.x;
        if (dv.y >= lo && dv.y < hi) csr_src[atomicAdd(&cursor[dv.y], 1)] = sv.y;
        if (dv.z >= lo && dv.z < hi) csr_src[atomicAdd(&cursor[dv.z], 1)] = sv.z;
        if (dv.w >= lo && dv.w < hi) csr_src[atomicAdd(&cursor[dv.w], 1)] = sv.w;
    }
}

// fill pad slots with the zero-row index N_NODES
__global__ void k_pad(const int* __restrict__ offsets, const int* __restrict__ cursor,
                      int* __restrict__ csr_src) {
    int i = blockIdx.x * blockDim.x + threadIdx.x;
    if (i >= N_NODES) return;
    int e = offsets[i + 1];
    for (int j = cursor[i]; j < e; ++j) csr_src[j] = N_NODES;
}

// aggx[n,f] = sx[n,f] + sum over incoming neighbors; 8 lanes/node, unroll x8
__global__ void k_gather1(const f16* __restrict__ sx, const int* __restrict__ offsets,
                          const int* __restrict__ csr_src, float* __restrict__ aggx) {
    int idx = blockIdx.x * blockDim.x + threadIdx.x;
    if (idx >= N_NODES * 8) return;
    int n = idx >> 3;
    int f = idx & 7;
    float acc = (float)sx[(n << 3) + f];
    int b = offsets[n], e = offsets[n + 1];
    for (int j = b; j < e; j += 8) {
        const int4* p = (const int4*)(csr_src + j);
        int4 ia = p[0], ib = p[1];
        float v0 = (float)sx[(ia.x << 3) + f], v1 = (float)sx[(ia.y << 3) + f];
        float v2 = (float)sx[(ia.z << 3) + f], v3 = (float)sx[(ia.w << 3) + f];
        float v4 = (float)sx[(ib.x << 3) + f], v5 = (float)sx[(ib.y << 3) + f];
        float v6 = (float)sx[(ib.z << 3) + f], v7 = (float)sx[(ib.w << 3) + f];
        acc += ((v0 + v1) + (v2 + v3)) + ((v4 + v5) + (v6 + v7));
    }
    aggx[(n << 3) + f] = acc;
}

// fused: h1 = lrelu(dis*(aggx@W1)+b1) (LDS only), t2 = dis*(h1@W2) in fp16
__global__ void k_h1t2(const float* __restrict__ aggx, const float* __restrict__ W1,
                       const float* __restrict__ b1, const float* __restrict__ W2,
                       const float* __restrict__ dis, f16* __restrict__ t2) {
    __shared__ float sW1[IN_F * H1];
    __shared__ float sb1[H1];
    __shared__ float sW2[H1 * H2];
    __shared__ float sh1[8][H1];
    int tid = threadIdx.x;
    for (int i = tid; i < IN_F * H1; i += 256) sW1[i] = W1[i];
    if (tid < H1) sb1[tid] = b1[tid];
    for (int i = tid; i < H1 * H2; i += 256) sW2[i] = W2[i];
    int loc = tid >> 5;
    int lane = tid & 31;
    int n = blockIdx.x * 8 + loc;
    bool ok = n < N_NODES;
    float a[IN_F];
    float dn = 0.0f;
    if (ok) {
        dn = dis[n];
#pragma unroll
        for (int j = 0; j < IN_F; ++j) a[j] = aggx[n * SXS + j];
    }
    __syncthreads();
    if (ok) {
#pragma unroll
        for (int kk = 0; kk < 2; ++kk) {
            int k = lane + kk * 32;
            float s = 0.0f;
#pragma unroll
            for (int j = 0; j < IN_F; ++j) s += a[j] * sW1[j * H1 + k];
            sh1[loc][k] = lrelu(s * dn + sb1[k]);
        }
    }
    __syncthreads();
    if (ok) {
        float s = 0.0f;
#pragma unroll
        for (int k = 0; k < H1; ++k) s += sh1[loc][k] * sW2[k * H2 + lane];
        t2[n * H2 + lane] = (f16)(s * dn);
    }
}

// agg2 gather (unroll x16) + lrelu + LDS-deduped mean-pool accumulation
__global__ void k_gather2(const f16* __restrict__ t2, const int* __restrict__ offsets,
                          const int* __restrict__ csr_src, const float* __restrict__ dis,
                          const float* __restrict__ b2, const int* __restrict__ batch,
                          float* __restrict__ gsum, float* __restrict__ gcnt) {
    __shared__ float sv[8][H2];
    __shared__ int sg[8];
    int idx = blockIdx.x * blockDim.x + threadIdx.x;
    int n = idx >> 5;
    int f = idx & 31;
    float acc = (float)t2[(n << 5) + f];
    int b = offsets[n], e = offsets[n + 1];
    int j = b;
    for (; j + 16 <= e; j += 16) {
        const int4* p = (const int4*)(csr_src + j);
        int4 ia = p[0], ib = p[1], ic = p[2], id = p[3];
        float v0 = (float)t2[(ia.x << 5) + f], v1 = (float)t2[(ia.y << 5) + f];
        float v2 = (float)t2[(ia.z << 5) + f], v3 = (float)t2[(ia.w << 5) + f];
        float v4 = (float)t2[(ib.x << 5) + f], v5 = (float)t2[(ib.y << 5) + f];
        float v6 = (float)t2[(ib.z << 5) + f], v7 = (float)t2[(ib.w << 5) + f];
        float v8 = (float)t2[(ic.x << 5) + f], v9 = (float)t2[(ic.y << 5) + f];
        float va = (float)t2[(ic.z << 5) + f], vb = (float)t2[(ic.w << 5) + f];
        float vc = (float)t2[(id.x << 5) + f], vd = (float)t2[(id.y << 5) + f];
        float ve = (float)t2[(id.z << 5) + f], vf = (float)t2[(id.w << 5) + f];
        acc += (((v0 + v1) + (v2 + v3)) + ((v4 + v5) + (v6 + v7)))
             + (((v8 + v9) + (va + vb)) + ((vc + vd) + (ve + vf)));
    }
    if (j < e) {   // one remaining 8-chunk (lists are 8-aligned)
        const int4* p = (const int4*)(csr_src + j);
        int4 ia = p[0], ib = p[1];
        float v0 = (float)t2[(ia.x << 5) + f], v1 = (float)t2[(ia.y << 5) + f];
        float v2 = (float)t2[(ia.z << 5) + f], v3 = (float)t2[(ia.w << 5) + f];
        float v4 = (float)t2[(ib.x << 5) + f], v5 = (float)t2[(ib.y << 5) + f];
        float v6 = (float)t2[(ib.z << 5) + f], v7 = (float)t2[(ib.w << 5) + f];
        acc += ((v0 + v1) + (v2 + v3)) + ((v4 + v5) + (v6 + v7));
    }
    float v = lrelu(acc * dis[n] + b2[f]);
    int g = batch[n];
    int loc = threadIdx.x >> 5;
    sv[loc][f] = v;
    if (f == 0) sg[loc] = g;
    __syncthreads();
    bool leader = true;
    for (int l = 0; l < loc; ++l) leader &= (sg[l] != g);
    if (leader) {
        float s = v;
        float c = 1.0f;
        for (int l = loc + 1; l < 8; ++l)
            if (sg[l] == g) { s += sv[l][f]; c += 1.0f; }
        atomicAdd(&gsum[g * H2 + f], s);
        if (f == 0) atomicAdd(&gcnt[g], c);
    }
}

__global__ void k_final(const float* __restrict__ gsum, const float* __restrict__ gcnt,
                        const float* __restrict__ Wlin, const float* __restrict__ blin,
                        float* __restrict__ out) {
    int idx = blockIdx.x * blockDim.x + threadIdx.x;
    if (idx >= N_GRAPHS * 2) return;
    int g = idx >> 1;
    int t = idx & 1;
    float inv = 1.0f / fmaxf(gcnt[g], 1.0f);
    float s = blin[t];
#pragma unroll
    for (int f = 0; f < H2; ++f)
        s += gsum[g * H2 + f] * inv * Wlin[f * 2 + t];
    out[idx] = s;
}

static inline int cdiv(long long a, int b) { return (int)((a + b - 1) / b); }

extern "C" void kernel_launch(void* const* d_in, const int* in_sizes, int n_in,
                              void* d_out, int out_size, void* d_ws, size_t ws_size,
                              hipStream_t stream) {
    const float* x    = (const float*)d_in[0];
    const int*   ei   = (const int*)d_in[1];
    const int*   batch= (const int*)d_in[2];
    const float* W1   = (const float*)d_in[3];
    const float* b1   = (const float*)d_in[4];
    const float* W2   = (const float*)d_in[5];
    const float* b2   = (const float*)d_in[6];
    const float* Wlin = (const float*)d_in[7];
    const float* blin = (const float*)d_in[8];
    float* out = (float*)d_out;

    const int* src = ei;
    const int* dst = ei + N_EDGES;

    // ---- workspace layout ----
    // fp16 tables first (t2 64B rows incl. zero row N, sx 16B rows incl. zero row N)
    f16*   t2   = (f16*)d_ws;                           // 32*(N+1) halves
    f16*   sx   = t2 + 32LL * (N_NODES + 1);            // 8*(N+1) halves
    float* dis  = (float*)(sx + 8LL * (N_NODES + 1));   // N floats
    float* aggx = dis + N_NODES;                        // 8N floats
    float* gsum = aggx + 8LL * N_NODES;                 // 32G
    float* gcnt = gsum + (long long)N_GRAPHS * H2;      // G
    // 16B-align the int region (csr_src int4 loads)
    size_t ioff = ((size_t)(gcnt + N_GRAPHS) + 15) & ~(size_t)15;
    int*  csr_src = (int*)ioff;                         // CSR_CAP
    int*  deg_i   = csr_src + CSR_CAP;                  // N
    int*  offsets = deg_i + N_NODES;                    // N+1
    int*  cursor  = offsets + N_NODES + 1;              // N
    int*  bsum    = cursor + N_NODES;                   // 128
    int*  bscan   = bsum + 128;                         // 128

    const int B = 256;

    hipMemsetAsync(deg_i, 0, sizeof(int) * N_NODES, stream);
    hipMemsetAsync(gsum, 0, sizeof(float) * (N_GRAPHS * H2 + N_GRAPHS), stream);
    hipMemsetAsync(t2 + 32LL * N_NODES, 0, 32 * sizeof(f16), stream);  // zero row
    hipMemsetAsync(sx + 8LL * N_NODES, 0, 8 * sizeof(f16), stream);    // zero row

    k_count<<<2048, B, 0, stream>>>(dst, deg_i);
    k_bsum<<<SCAN_NB, SCAN_BLK, 0, stream>>>(deg_i, bsum);
    k_bscan<<<1, 128, 0, stream>>>(bsum, bscan);
    k_csr<<<SCAN_NB, SCAN_BLK, 0, stream>>>(deg_i, bscan, x, offsets, cursor, dis, sx);
    k_place<<<2048, B, 0, stream>>>(src, dst, cursor, csr_src);
    k_pad<<<cdiv(N_NODES, B), B, 0, stream>>>(offsets, cursor, csr_src);

    k_gather1<<<cdiv((long long)N_NODES * 8, B), B, 0, stream>>>(sx, offsets, csr_src, aggx);
    k_h1t2<<<cdiv(N_NODES, 8), B, 0, stream>>>(aggx, W1, b1, W2, dis, t2);
    k_gather2<<<cdiv((long long)N_NODES * H2, B), B, 0, stream>>>(t2, offsets, csr_src, dis,
                                                                  b2, batch, gsum, gcnt);
    k_final<<<cdiv(N_GRAPHS * 2, B), B, 0, stream>>>(gsum, gcnt, Wlin, blin, out);
}

// Round 6
// 401.114 us; speedup vs baseline: 3.3892x; 1.0103x over previous
//
#include <hip/hip_runtime.h>

// GCN forward, CSR-gather formulation, round 5.
// fp16 gather tables (t2, sx), 8-aligned padded adjacency lists,
// LDS-deduplicated pool atomics, XCD-partitioned histogram/placement.

#define N_NODES 100000
#define N_EDGES 3200000
#define N_GRAPHS 1024
#define IN_F 6
#define SXS 8            // padded row stride for sx/aggx
#define H1 64
#define H2 32
#define SLOPE 0.01f

#define SCAN_BLK 1024
#define SCAN_NB ((N_NODES + SCAN_BLK - 1) / SCAN_BLK)   // 98
#define NXCD 8
#define NODES_PER_XCD (N_NODES / NXCD)                  // 12500
#define CSR_CAP 4000000                                 // >= E + 7N

typedef _Float16 f16;

static __device__ __forceinline__ float lrelu(float v) {
    return v > 0.0f ? v : SLOPE * v;
}

// XCD-partitioned histogram of incoming edges per node
__global__ void k_count(const int* __restrict__ dst, int* __restrict__ deg_i) {
    int xcd = blockIdx.x & (NXCD - 1);
    int lo = xcd * NODES_PER_XCD;
    int hi = lo + NODES_PER_XCD;
    int grp = blockIdx.x >> 3;
    int ngrp = gridDim.x >> 3;
    int t = grp * blockDim.x + threadIdx.x;
    int stride = ngrp * blockDim.x;
    const int4* d4 = (const int4*)dst;
    for (int i = t; i < N_EDGES / 4; i += stride) {
        int4 v = d4[i];
        if (v.x >= lo && v.x < hi) atomicAdd(&deg_i[v.x], 1);
        if (v.y >= lo && v.y < hi) atomicAdd(&deg_i[v.y], 1);
        if (v.z >= lo && v.z < hi) atomicAdd(&deg_i[v.z], 1);
        if (v.w >= lo && v.w < hi) atomicAdd(&deg_i[v.w], 1);
    }
}

// per-block sums of 8-padded degrees
__global__ void k_bsum(const int* __restrict__ deg_i, int* __restrict__ bsum) {
    __shared__ int red[SCAN_BLK];
    int tid = threadIdx.x;
    int i = blockIdx.x * SCAN_BLK + tid;
    red[tid] = (i < N_NODES) ? ((deg_i[i] + 7) & ~7) : 0;
    __syncthreads();
    for (int s = SCAN_BLK / 2; s > 0; s >>= 1) {
        if (tid < s) red[tid] += red[tid + s];
        __syncthreads();
    }
    if (tid == 0) bsum[blockIdx.x] = red[0];
}

// exclusive scan of block sums (1 block, 128 threads)
__global__ void k_bscan(const int* __restrict__ bsum, int* __restrict__ bscan) {
    __shared__ int sc[128];
    int tid = threadIdx.x;
    int v = (tid < SCAN_NB) ? bsum[tid] : 0;
    sc[tid] = v;
    __syncthreads();
    for (int off = 1; off < 128; off <<= 1) {
        int t = 0;
        if (tid >= off) t = sc[tid - off];
        __syncthreads();
        if (tid >= off) sc[tid] += t;
        __syncthreads();
    }
    if (tid < SCAN_NB) bscan[tid] = sc[tid] - v;   // exclusive
}

// per-block scan of padded degrees -> offsets/cursor; dis = rsqrt(deg+1);
// sx = x*dis in fp16 (stride 8, zero-pad)
__global__ void k_csr(const int* __restrict__ deg_i, const int* __restrict__ bscan,
                      const float* __restrict__ x,
                      int* __restrict__ offsets, int* __restrict__ cursor,
                      float* __restrict__ dis, f16* __restrict__ sx) {
    __shared__ int sc[SCAN_BLK];
    int tid = threadIdx.x;
    int i = blockIdx.x * SCAN_BLK + tid;
    int dv = (i < N_NODES) ? deg_i[i] : 0;
    int v = (i < N_NODES) ? ((dv + 7) & ~7) : 0;
    sc[tid] = v;
    __syncthreads();
    for (int off = 1; off < SCAN_BLK; off <<= 1) {
        int t = 0;
        if (tid >= off) t = sc[tid - off];
        __syncthreads();
        if (tid >= off) sc[tid] += t;
        __syncthreads();
    }
    int base = bscan[blockIdx.x];
    if (i < N_NODES) {
        int excl = base + sc[tid] - v;
        offsets[i] = excl;
        cursor[i] = excl;
        float dn = rsqrtf((float)(dv + 1));
        dis[i] = dn;
#pragma unroll
        for (int j = 0; j < IN_F; ++j)
            sx[i * SXS + j] = (f16)(x[i * IN_F + j] * dn);
        sx[i * SXS + 6] = (f16)0.0f;
        sx[i * SXS + 7] = (f16)0.0f;
        if (i == N_NODES - 1) offsets[N_NODES] = base + sc[tid];
    }
}

// XCD-partitioned CSR placement
__global__ void k_place(const int* __restrict__ src, const int* __restrict__ dst,
                        int* __restrict__ cursor, int* __restrict__ csr_src) {
    int xcd = blockIdx.x & (NXCD - 1);
    int lo = xcd * NODES_PER_XCD;
    int hi = lo + NODES_PER_XCD;
    int grp = blockIdx.x >> 3;
    int ngrp = gridDim.x >> 3;
    int t = grp * blockDim.x + threadIdx.x;
    int stride = ngrp * blockDim.x;
    const int4* d4 = (const int4*)dst;
    const int4* s4 = (const int4*)src;
    for (int i = t; i < N_EDGES / 4; i += stride) {
        int4 dv = d4[i];
        int4 sv = s4[i];
        if (dv.x >= lo && dv.x < hi) csr_src[atomicAdd(&cursor[dv.x], 1)] = sv.x;
        if (dv.y >= lo && dv.y < hi) csr_src[atomicAdd(&cursor[dv.y], 1)] = sv.y;
        if (dv.z >= lo && dv.z < hi) csr_src[atomicAdd(&cursor[dv.z], 1)] = sv.z;
        if (dv.w >= lo && dv.w < hi) csr_src[atomicAdd(&cursor[dv.w], 1)] = sv.w;
    }
}

// fill pad slots with the zero-row index N_NODES
__global__ void k_pad(const int* __restrict__ offsets, const int* __restrict__ cursor,
                      int* __restrict__ csr_src) {
    int i = blockIdx.x * blockDim.x + threadIdx.x;
    if (i >= N_NODES) return;
    int e = offsets[i + 1];
    for (int j = cursor[i]; j < e; ++j) csr_src[j] = N_NODES;
}

// aggx[n,f] = sx[n,f] + sum over incoming neighbors; 8 lanes/node, unroll x8
__global__ void k_gather1(const f16* __restrict__ sx, const int* __restrict__ offsets,
                          const int* __restrict__ csr_src, float* __restrict__ aggx) {
    int idx = blockIdx.x * blockDim.x + threadIdx.x;
    if (idx >= N_NODES * 8) return;
    int n = idx >> 3;
    int f = idx & 7;
    float acc = (float)sx[(n << 3) + f];
    int b = offsets[n], e = offsets[n + 1];
    for (int j = b; j < e; j += 8) {
        const int4* p = (const int4*)(csr_src + j);
        int4 ia = p[0], ib = p[1];
        float v0 = (float)sx[(ia.x << 3) + f], v1 = (float)sx[(ia.y << 3) + f];
        float v2 = (float)sx[(ia.z << 3) + f], v3 = (float)sx[(ia.w << 3) + f];
        float v4 = (float)sx[(ib.x << 3) + f], v5 = (float)sx[(ib.y << 3) + f];
        float v6 = (float)sx[(ib.z << 3) + f], v7 = (float)sx[(ib.w << 3) + f];
        acc += ((v0 + v1) + (v2 + v3)) + ((v4 + v5) + (v6 + v7));
    }
    aggx[(n << 3) + f] = acc;
}

// fused: h1 = lrelu(dis*(aggx@W1)+b1) (LDS only), t2 = dis*(h1@W2) in fp16
__global__ void k_h1t2(const float* __restrict__ aggx, const float* __restrict__ W1,
                       const float* __restrict__ b1, const float* __restrict__ W2,
                       const float* __restrict__ dis, f16* __restrict__ t2) {
    __shared__ float sW1[IN_F * H1];
    __shared__ float sb1[H1];
    __shared__ float sW2[H1 * H2];
    __shared__ float sh1[8][H1];
    int tid = threadIdx.x;
    for (int i = tid; i < IN_F * H1; i += 256) sW1[i] = W1[i];
    if (tid < H1) sb1[tid] = b1[tid];
    for (int i = tid; i < H1 * H2; i += 256) sW2[i] = W2[i];
    int loc = tid >> 5;
    int lane = tid & 31;
    int n = blockIdx.x * 8 + loc;
    bool ok = n < N_NODES;
    float a[IN_F];
    float dn = 0.0f;
    if (ok) {
        dn = dis[n];
#pragma unroll
        for (int j = 0; j < IN_F; ++j) a[j] = aggx[n * SXS + j];
    }
    __syncthreads();
    if (ok) {
#pragma unroll
        for (int kk = 0; kk < 2; ++kk) {
            int k = lane + kk * 32;
            float s = 0.0f;
#pragma unroll
            for (int j = 0; j < IN_F; ++j) s += a[j] * sW1[j * H1 + k];
            sh1[loc][k] = lrelu(s * dn + sb1[k]);
        }
    }
    __syncthreads();
    if (ok) {
        float s = 0.0f;
#pragma unroll
        for (int k = 0; k < H1; ++k) s += sh1[loc][k] * sW2[k * H2 + lane];
        t2[n * H2 + lane] = (f16)(s * dn);
    }
}

// agg2 gather (unroll x16) + lrelu + LDS-deduped mean-pool accumulation
__global__ void k_gather2(const f16* __restrict__ t2, const int* __restrict__ offsets,
                          const int* __restrict__ csr_src, const float* __restrict__ dis,
                          const float* __restrict__ b2, const int* __restrict__ batch,
                          float* __restrict__ gsum, float* __restrict__ gcnt) {
    __shared__ float sv[8][H2];
    __shared__ int sg[8];
    int idx = blockIdx.x * blockDim.x + threadIdx.x;
    int n = idx >> 5;
    int f = idx & 31;
    float acc = (float)t2[(n << 5) + f];
    int b = offsets[n], e = offsets[n + 1];
    int j = b;
    for (; j + 16 <= e; j += 16) {
        const int4* p = (const int4*)(csr_src + j);
        int4 ia = p[0], ib = p[1], ic = p[2], id = p[3];
        float v0 = (float)t2[(ia.x << 5) + f], v1 = (float)t2[(ia.y << 5) + f];
        float v2 = (float)t2[(ia.z << 5) + f], v3 = (float)t2[(ia.w << 5) + f];
        float v4 = (float)t2[(ib.x << 5) + f], v5 = (float)t2[(ib.y << 5) + f];
        float v6 = (float)t2[(ib.z << 5) + f], v7 = (float)t2[(ib.w << 5) + f];
        float v8 = (float)t2[(ic.x << 5) + f], v9 = (float)t2[(ic.y << 5) + f];
        float va = (float)t2[(ic.z << 5) + f], vb = (float)t2[(ic.w << 5) + f];
        float vc = (float)t2[(id.x << 5) + f], vd = (float)t2[(id.y << 5) + f];
        float ve = (float)t2[(id.z << 5) + f], vf = (float)t2[(id.w << 5) + f];
        acc += (((v0 + v1) + (v2 + v3)) + ((v4 + v5) + (v6 + v7)))
             + (((v8 + v9) + (va + vb)) + ((vc + vd) + (ve + vf)));
    }
    if (j < e) {   // one remaining 8-chunk (lists are 8-aligned)
        const int4* p = (const int4*)(csr_src + j);
        int4 ia = p[0], ib = p[1];
        float v0 = (float)t2[(ia.x << 5) + f], v1 = (float)t2[(ia.y << 5) + f];
        float v2 = (float)t2[(ia.z << 5) + f], v3 = (float)t2[(ia.w << 5) + f];
        float v4 = (float)t2[(ib.x << 5) + f], v5 = (float)t2[(ib.y << 5) + f];
        float v6 = (float)t2[(ib.z << 5) + f], v7 = (float)t2[(ib.w << 5) + f];
        acc += ((v0 + v1) + (v2 + v3)) + ((v4 + v5) + (v6 + v7));
    }
    float v = lrelu(acc * dis[n] + b2[f]);
    int g = batch[n];
    int loc = threadIdx.x >> 5;
    sv[loc][f] = v;
    if (f == 0) sg[loc] = g;
    __syncthreads();
    bool leader = true;
    for (int l = 0; l < loc; ++l) leader &= (sg[l] != g);
    if (leader) {
        float s = v;
        float c = 1.0f;
        for (int l = loc + 1; l < 8; ++l)
            if (sg[l] == g) { s += sv[l][f]; c += 1.0f; }
        atomicAdd(&gsum[g * H2 + f], s);
        if (f == 0) atomicAdd(&gcnt[g], c);
    }
}

__global__ void k_final(const float* __restrict__ gsum, const float* __restrict__ gcnt,
                        const float* __restrict__ Wlin, const float* __restrict__ blin,
                        float* __restrict__ out) {
    int idx = blockIdx.x * blockDim.x + threadIdx.x;
    if (idx >= N_GRAPHS * 2) return;
    int g = idx >> 1;
    int t = idx & 1;
    float inv = 1.0f / fmaxf(gcnt[g], 1.0f);
    float s = blin[t];
#pragma unroll
    for (int f = 0; f < H2; ++f)
        s += gsum[g * H2 + f] * inv * Wlin[f * 2 + t];
    out[idx] = s;
}

static inline int cdiv(long long a, int b) { return (int)((a + b - 1) / b); }

extern "C" void kernel_launch(void* const* d_in, const int* in_sizes, int n_in,
                              void* d_out, int out_size, void* d_ws, size_t ws_size,
                              hipStream_t stream) {
    const float* x    = (const float*)d_in[0];
    const int*   ei   = (const int*)d_in[1];
    const int*   batch= (const int*)d_in[2];
    const float* W1   = (const float*)d_in[3];
    const float* b1   = (const float*)d_in[4];
    const float* W2   = (const float*)d_in[5];
    const float* b2   = (const float*)d_in[6];
    const float* Wlin = (const float*)d_in[7];
    const float* blin = (const float*)d_in[8];
    float* out = (float*)d_out;

    const int* src = ei;
    const int* dst = ei + N_EDGES;

    // ---- workspace layout ----
    // fp16 tables first (t2 64B rows incl. zero row N, sx 16B rows incl. zero row N)
    f16*   t2   = (f16*)d_ws;                           // 32*(N+1) halves
    f16*   sx   = t2 + 32LL * (N_NODES + 1);            // 8*(N+1) halves
    float* dis  = (float*)(sx + 8LL * (N_NODES + 1));   // N floats
    float* aggx = dis + N_NODES;                        // 8N floats
    float* gsum = aggx + 8LL * N_NODES;                 // 32G
    float* gcnt = gsum + (long long)N_GRAPHS * H2;      // G
    // 16B-align the int region (csr_src int4 loads)
    size_t ioff = ((size_t)(gcnt + N_GRAPHS) + 15) & ~(size_t)15;
    int*  csr_src = (int*)ioff;                         // CSR_CAP
    int*  deg_i   = csr_src + CSR_CAP;                  // N
    int*  offsets = deg_i + N_NODES;                    // N+1
    int*  cursor  = offsets + N_NODES + 1;              // N
    int*  bsum    = cursor + N_NODES;                   // 128
    int*  bscan   = bsum + 128;                         // 128

    const int B = 256;

    hipMemsetAsync(deg_i, 0, sizeof(int) * N_NODES, stream);
    hipMemsetAsync(gsum, 0, sizeof(float) * (N_GRAPHS * H2 + N_GRAPHS), stream);
    hipMemsetAsync(t2 + 32LL * N_NODES, 0, 32 * sizeof(f16), stream);  // zero row
    hipMemsetAsync(sx + 8LL * N_NODES, 0, 8 * sizeof(f16), stream);    // zero row

    k_count<<<2048, B, 0, stream>>>(dst, deg_i);
    k_bsum<<<SCAN_NB, SCAN_BLK, 0, stream>>>(deg_i, bsum);
    k_bscan<<<1, 128, 0, stream>>>(bsum, bscan);
    k_csr<<<SCAN_NB, SCAN_BLK, 0, stream>>>(deg_i, bscan, x, offsets, cursor, dis, sx);
    k_place<<<2048, B, 0, stream>>>(src, dst, cursor, csr_src);
    k_pad<<<cdiv(N_NODES, B), B, 0, stream>>>(offsets, cursor, csr_src);

    k_gather1<<<cdiv((long long)N_NODES * 8, B), B, 0, stream>>>(sx, offsets, csr_src, aggx);
    k_h1t2<<<cdiv(N_NODES, 8), B, 0, stream>>>(aggx, W1, b1, W2, dis, t2);
    k_gather2<<<cdiv((long long)N_NODES * H2, B), B, 0, stream>>>(t2, offsets, csr_src, dis,
                                                                  b2, batch, gsum, gcnt);
    k_final<<<cdiv(N_GRAPHS * 2, B), B, 0, stream>>>(gsum, gcnt, Wlin, blin, out);
}